// Round 12
// baseline (474.133 us; speedup 1.0000x reference)
//
#include <hip/hip_runtime.h>
#include <hip/hip_bf16.h>
#include <cstdint>

typedef __attribute__((ext_vector_type(4))) float f32x4;
typedef __attribute__((ext_vector_type(8))) short s16x8;

#define LOG2E 1.44269504088896340736f

#define WAITV0 asm volatile("s_waitcnt vmcnt(0)" ::: "memory")
#define WAITV4 asm volatile("s_waitcnt vmcnt(4)" ::: "memory")
#define WAITLG asm volatile("s_waitcnt lgkmcnt(0)" ::: "memory")

__device__ __forceinline__ unsigned short f2bf(float f) {
    unsigned int u = __builtin_bit_cast(unsigned int, f);
    u += 0x7FFFu + ((u >> 16) & 1u);
    return (unsigned short)(u >> 16);
}
__device__ __forceinline__ float bf2f(unsigned short u) {
    return __builtin_bit_cast(float, (unsigned int)u << 16);
}
__device__ __forceinline__ void gload_lds16(const void* g, void* l) {
    __builtin_amdgcn_global_load_lds(
        (const __attribute__((address_space(1))) unsigned int*)g,
        (__attribute__((address_space(3))) unsigned int*)l, 16, 0, 0);
}

// ---------------- prep kernels (ROUND-5 VERSIONS — proven 4.88e-4) ----------------

__global__ void convert_x_kernel(const float* __restrict__ x,
                                 unsigned short* __restrict__ xb, int n4) {
    int i = blockIdx.x * blockDim.x + threadIdx.x;
    if (i < n4) {
        const float4 v = reinterpret_cast<const float4*>(x)[i];
        ushort4 o;
        o.x = f2bf(v.x); o.y = f2bf(v.y); o.z = f2bf(v.z); o.w = f2bf(v.w);
        reinterpret_cast<ushort4*>(xb)[i] = o;
    }
}

// WT layout: [3][512 n][512 k], WT[m][n][k] = W_m[k][n]  (bf16)
__global__ void transpose_w_kernel(const float* __restrict__ Wq,
                                   const float* __restrict__ Wk,
                                   const float* __restrict__ Wv,
                                   unsigned short* __restrict__ WT) {
    int i = blockIdx.x * blockDim.x + threadIdx.x;
    int m = i >> 18;
    int r = i & 262143;
    int n = r & 511;
    int k = r >> 9;
    const float* W = (m == 0) ? Wq : (m == 1) ? Wk : Wv;
    WT[(m << 18) + n * 512 + k] = f2bf(W[k * 512 + n]);
}

// ---------------- projection GEMM (ROUND-5 VERSION — proven 4.88e-4) ----------------
__global__ __launch_bounds__(256, 2) void proj_gemm_kernel(
    const unsigned short* __restrict__ xb,
    const unsigned short* __restrict__ WT,
    const float* __restrict__ bq, const float* __restrict__ bk, const float* __restrict__ bv,
    unsigned short* __restrict__ Qb, unsigned short* __restrict__ Kb,
    unsigned short* __restrict__ VT)
{
    const int z = blockIdx.z;
    const unsigned short* Wt = WT + (z << 18);
    const float* bias = (z == 0) ? bq : (z == 1) ? bk : bv;

    const int gm = blockIdx.x * 128;
    const int gn = blockIdx.y * 128;
    const int wave = threadIdx.x >> 6, lane = threadIdx.x & 63;
    const int wr = wave >> 1, wc = wave & 1;
    const int lr = lane & 15, lg = lane >> 4;
    const int row0 = gm + wr * 64;
    const int col0 = gn + wc * 64;

    f32x4 acc[4][4];
    #pragma unroll
    for (int mi = 0; mi < 4; mi++)
        #pragma unroll
        for (int ni = 0; ni < 4; ni++)
            acc[mi][ni] = (f32x4){0.f, 0.f, 0.f, 0.f};

    for (int k0 = 0; k0 < 512; k0 += 32) {
        s16x8 a[4], b[4];
        #pragma unroll
        for (int mi = 0; mi < 4; mi++)
            a[mi] = *reinterpret_cast<const s16x8*>(xb + (size_t)(row0 + mi * 16 + lr) * 512 + k0 + lg * 8);
        #pragma unroll
        for (int ni = 0; ni < 4; ni++)
            b[ni] = *reinterpret_cast<const s16x8*>(Wt + (size_t)(col0 + ni * 16 + lr) * 512 + k0 + lg * 8);
        #pragma unroll
        for (int mi = 0; mi < 4; mi++)
            #pragma unroll
            for (int ni = 0; ni < 4; ni++)
                acc[mi][ni] = __builtin_amdgcn_mfma_f32_16x16x32_bf16(a[mi], b[ni], acc[mi][ni], 0, 0, 0);
    }

    #pragma unroll
    for (int ni = 0; ni < 4; ni++) {
        const int col = col0 + ni * 16 + lr;
        const float bs = bias[col];
        #pragma unroll
        for (int mi = 0; mi < 4; mi++) {
            const int rowb = row0 + mi * 16 + lg * 4;
            if (z == 2) {
                unsigned short h[4];
                #pragma unroll
                for (int j = 0; j < 4; j++) h[j] = f2bf(acc[mi][ni][j] + bs);
                const int bb = rowb >> 11;
                const int nn = rowb & 2047;
                ushort4 o; o.x = h[0]; o.y = h[1]; o.z = h[2]; o.w = h[3];
                *reinterpret_cast<ushort4*>(VT + (size_t)bb * (512 * 2048) + (size_t)col * 2048 + nn) = o;
            } else {
                unsigned short* dst = (z == 0) ? Qb : Kb;
                #pragma unroll
                for (int j = 0; j < 4; j++)
                    dst[(size_t)(rowb + j) * 512 + col] = f2bf(acc[mi][ni][j] + bs);
            }
        }
    }
}

// ---------------- fused masked attention: K-direct + 128-d phases ----------------
// 512 blocks 1-D XCD-phased (4MB K/V working set per XCD, L2-resident).
// 8 waves: 0-3 S (QK^T with K DIRECT FROM L2 — no kring, no manual vmcnt),
//          4-7 O (PV from LDS V ring: 3 x 16KB chunks of 128 d, WAITV4 discipline).
// 4 phases per kv-tile (was 8): barriers 137 -> 69.
__global__ __launch_bounds__(512, 2) void attn_kernel(
    const unsigned short* __restrict__ Qb,
    const unsigned short* __restrict__ Kb,
    const unsigned short* __restrict__ VTb,
    const float* __restrict__ adj,
    const float* __restrict__ scale_p, const float* __restrict__ width_p,
    unsigned short* __restrict__ Op,
    float* __restrict__ Mp, float* __restrict__ Lp)
{
    const int bid = blockIdx.x;
    const int x8 = bid & 7, jj = bid >> 3;
    const int bk = x8 + 8 * (jj >> 5);
    const int qt = jj & 31;
    const int b    = bk >> 1;
    const int kvh  = bk & 1;
    const int wave = threadIdx.x >> 6;
    const int lane = threadIdx.x & 63;
    const int lr   = lane & 15;
    const int lg   = lane >> 4;

    // LDS carve: vring 3x16384 | pbuf [2][4][16][72] | corr [2][64]  (68096 total)
    __shared__ __align__(16) char smem[68096];
    char* vring = smem;
    unsigned short (*pbuf)[4][16][72] = (unsigned short (*)[4][16][72])(smem + 49152);
    float* corrbuf = (float*)(smem + 67584);

    if (wave < 4) {
        // ========= S path: QK^T (K direct from L2) + mask + online softmax =========
        const int sw = wave;
        const int q0 = qt * 64 + sw * 16;
        const unsigned short* Qrow = Qb + ((size_t)b * 2048 + q0) * 512;
        const char* Kg = (const char*)Kb + ((size_t)b * 2048 + (size_t)kvh * 1024) * 1024;
        const float* adj_b = adj + (size_t)b * 2048 * 2048
                           + (size_t)(q0 + lg * 4) * 2048 + (size_t)kvh * 1024 + lr;
        const float scl = *scale_p;
        const float nw  = -LOG2E / (*width_p);
        const float cf  = 0.044194173824159216f * LOG2E;

        s16x8 qf[16];
        #pragma unroll
        for (int ks = 0; ks < 16; ks++)
            qf[ks] = __builtin_nontemporal_load(
                reinterpret_cast<const s16x8*>(Qrow + (size_t)lr * 512 + ks * 32 + lg * 8));

        f32x4 sacc[4];
        #pragma unroll
        for (int nt = 0; nt < 4; nt++) sacc[nt] = (f32x4){0.f, 0.f, 0.f, 0.f};
        float m_[4] = {-1e30f, -1e30f, -1e30f, -1e30f};
        float l_[4] = {0.f, 0.f, 0.f, 0.f};

        __builtin_amdgcn_s_barrier();   // prologue (matches O)

        for (int t = 0; t < 16; ++t) {
            const int kv0 = t * 64;
            float av[4][4];
            #pragma unroll
            for (int p = 0; p < 4; ++p) {
                if (p == 0) {
                    // adj for this tile: used at p3 -> ~3 phases of compiler-managed cover
                    #pragma unroll
                    for (int nt = 0; nt < 4; nt++)
                        #pragma unroll
                        for (int j = 0; j < 4; j++)
                            av[nt][j] = __builtin_nontemporal_load(
                                &adj_b[(size_t)j * 2048 + kv0 + nt * 16]);
                }

                __builtin_amdgcn_s_setprio(1);
                #pragma unroll
                for (int ks = 0; ks < 4; ks++) {
                    const int idx = p * 4 + ks;
                    const s16x8 a = qf[idx];
                    #pragma unroll
                    for (int nt = 0; nt < 4; nt++) {
                        const s16x8 kf = *reinterpret_cast<const s16x8*>(
                            Kg + (size_t)(kv0 + nt * 16 + lr) * 1024 + idx * 64 + lg * 16);
                        sacc[nt] = __builtin_amdgcn_mfma_f32_16x16x32_bf16(a, kf, sacc[nt], 0, 0, 0);
                    }
                }
                __builtin_amdgcn_s_setprio(0);

                if (p == 3) {
                    // mask + online softmax; hand off P and corr via LDS
                    #pragma unroll
                    for (int nt = 0; nt < 4; nt++)
                        #pragma unroll
                        for (int j = 0; j < 4; j++) {
                            const float d = av[nt][j] - scl;
                            sacc[nt][j] = sacc[nt][j] * cf * exp2f(d * d * nw);
                        }
                    float corr[4];
                    #pragma unroll
                    for (int j = 0; j < 4; j++) {
                        float v = fmaxf(fmaxf(sacc[0][j], sacc[1][j]), fmaxf(sacc[2][j], sacc[3][j]));
                        #pragma unroll
                        for (int sh = 1; sh < 16; sh <<= 1) v = fmaxf(v, __shfl_xor(v, sh, 64));
                        const float mn = fmaxf(m_[j], v);
                        corr[j] = exp2f(m_[j] - mn);
                        m_[j] = mn;
                    }
                    #pragma unroll
                    for (int j = 0; j < 4; j++) {
                        float rs = 0.f;
                        #pragma unroll
                        for (int nt = 0; nt < 4; nt++) {
                            const float pv = exp2f(sacc[nt][j] - m_[j]);
                            pbuf[t & 1][sw][lg * 4 + j][nt * 16 + lr] = f2bf(pv);
                            rs += pv;
                        }
                        #pragma unroll
                        for (int sh = 1; sh < 16; sh <<= 1) rs += __shfl_xor(rs, sh, 64);
                        l_[j] = l_[j] * corr[j] + rs;
                    }
                    if (lr == 0) {
                        #pragma unroll
                        for (int j = 0; j < 4; j++)
                            corrbuf[(t & 1) * 64 + sw * 16 + lg * 4 + j] = corr[j];
                    }
                    #pragma unroll
                    for (int nt = 0; nt < 4; nt++) sacc[nt] = (f32x4){0.f, 0.f, 0.f, 0.f};
                    WAITLG;   // drain pbuf/corr ds_writes before barrier
                }
                __builtin_amdgcn_s_barrier();
            }
        }
        // trailing idle tile (4 barriers): O-waves finish PV(15)
        #pragma unroll
        for (int p = 0; p < 4; ++p) {
            WAITV0;
            __builtin_amdgcn_s_barrier();
        }
        const size_t prow0 = (size_t)kvh * 16384 + (size_t)b * 2048 + q0;
        if (lr == 0) {
            #pragma unroll
            for (int j = 0; j < 4; j++) {
                Mp[prow0 + lg * 4 + j] = m_[j];
                Lp[prow0 + lg * 4 + j] = l_[j];
            }
        }
    } else {
        // ========= O path: PV from 16KB LDS V-chunks (ring-3, depth-2) =========
        const int ow = wave - 4;
        const int q0 = qt * 64 + ow * 16;
        const char* Vg = (const char*)VTb + ((size_t)b * 512 * 2048 + (size_t)kvh * 1024) * 2;

        // stage V chunk c (tile c>>2, d-block c&3: 128 d rows x 64 kv) into ring slot
        auto stage_v = [&](int slot, int c) {
            char* dstb = vring + slot * 16384;
            const int kvt = (c >> 2) * 64;
            const int dr0 = (c & 3) * 128;
            #pragma unroll
            for (int i = 0; i < 4; i++) {
                const int sl  = ow * 4 + i;              // 0..15
                const int row = sl * 8 + (lane >> 3);    // 0..127
                const int colb = (lane & 7) * 16;
                gload_lds16(Vg + (size_t)(dr0 + row) * 4096 + (size_t)kvt * 2 + (colb ^ ((row & 7) << 4)),
                            dstb + sl * 1024);
            }
        };

        f32x4 oacc[32];
        #pragma unroll
        for (int i = 0; i < 32; i++) oacc[i] = (f32x4){0.f, 0.f, 0.f, 0.f};
        s16x8 pa0{}, pa1{};

        __builtin_amdgcn_s_barrier();   // prologue (matches S)

        // idle tile t=0: start V stream (chunk0->slot1 at p2, chunk1->slot2 at p3)
        #pragma unroll
        for (int p = 0; p < 4; ++p) {
            if (p == 2) stage_v(1, 0);
            if (p == 3) stage_v(2, 1);
            WAITV4;
            __builtin_amdgcn_s_barrier();
        }

        int ss = 0;   // next stage slot (chunk2 -> slot 0; slot(c) = (c+1)%3)
        int cs = 1;   // compute slot for chunk 0
        for (int t = 1; t < 17; ++t) {
            #pragma unroll
            for (int p = 0; p < 4; ++p) {
                const int c_s = t * 4 + p - 2;          // stage 2 chunks ahead
                const bool do_stage = (c_s <= 63);
                if (do_stage) { stage_v(ss, c_s); ss = (ss == 2) ? 0 : ss + 1; }

                if (p == 0) {
                    const float* cl = corrbuf + ((t - 1) & 1) * 64 + ow * 16;
                    float c_[4];
                    #pragma unroll
                    for (int j = 0; j < 4; j++) c_[j] = cl[lg * 4 + j];
                    const unsigned short* pb = &pbuf[(t - 1) & 1][ow][0][0];
                    pa0 = *reinterpret_cast<const s16x8*>(pb + lr * 72 + lg * 8);
                    pa1 = *reinterpret_cast<const s16x8*>(pb + lr * 72 + 32 + lg * 8);
                    const bool need = __any(c_[0] < 1.f || c_[1] < 1.f || c_[2] < 1.f || c_[3] < 1.f);
                    if (need) {
                        #pragma unroll
                        for (int f = 0; f < 32; f++)
                            #pragma unroll
                            for (int j = 0; j < 4; j++) oacc[f][j] *= c_[j];
                    }
                }

                const char* vb_ = vring + cs * 16384;
                cs = (cs == 2) ? 0 : cs + 1;
                __builtin_amdgcn_s_setprio(1);
                #pragma unroll
                for (int ks2 = 0; ks2 < 2; ks2++) {
                    const s16x8 pa = (ks2 == 0) ? pa0 : pa1;
                    #pragma unroll
                    for (int df2 = 0; df2 < 8; df2++) {
                        const int row = df2 * 16 + lr;   // 0..127 within chunk
                        const int cbyte = ks2 * 64 + lg * 16;
                        const s16x8 vf = *reinterpret_cast<const s16x8*>(
                            vb_ + row * 128 + (cbyte ^ ((row & 7) << 4)));
                        oacc[p * 8 + df2] = __builtin_amdgcn_mfma_f32_16x16x32_bf16(pa, vf, oacc[p * 8 + df2], 0, 0, 0);
                    }
                }
                __builtin_amdgcn_s_setprio(0);

                if (do_stage) { WAITV4; } else { WAITV0; }
                __builtin_amdgcn_s_barrier();
            }
        }

        // ---- epilogue: LDS-transpose -> full-line nontemporal Op stores ----
        unsigned short* lds_t = (unsigned short*)smem + (size_t)ow * 4224;  // 16 x 264
        const size_t prow0 = (size_t)kvh * 16384 + (size_t)b * 2048 + q0;
        #pragma unroll
        for (int h = 0; h < 2; ++h) {
            #pragma unroll
            for (int dd = 0; dd < 16; ++dd) {
                const int df = h * 16 + dd;
                #pragma unroll
                for (int j = 0; j < 4; ++j)
                    lds_t[(lg * 4 + j) * 264 + dd * 16 + lr] = f2bf(oacc[df][j]);
            }
            #pragma unroll
            for (int g2 = 0; g2 < 2; ++g2) {
                const int r16  = g2 * 8 + (lane >> 3);
                const int colu = (lane & 7) * 8;
                unsigned short* oprow = Op + (prow0 + r16) * 512 + h * 256;
                #pragma unroll
                for (int k = 0; k < 4; ++k) {
                    const s16x8 v = *reinterpret_cast<const s16x8*>(&lds_t[r16 * 264 + colu + k * 64]);
                    __builtin_nontemporal_store(v, reinterpret_cast<s16x8*>(oprow + colu + k * 64));
                }
            }
        }
    }
}

// ---------------- combine ----------------
__global__ void combine_kernel(const unsigned short* __restrict__ Op,
                               const float* __restrict__ Mp, const float* __restrict__ Lp,
                               float* __restrict__ out) {
    const int idx = blockIdx.x * 256 + threadIdx.x;
    const int r   = idx >> 6;
    const int c8  = (idx & 63) * 8;
    const float m0 = Mp[r], m1 = Mp[16384 + r];
    const float l0 = Lp[r], l1 = Lp[16384 + r];
    const float M  = fmaxf(m0, m1);
    const float e0 = exp2f(m0 - M), e1 = exp2f(m1 - M);
    const float invL = 1.f / (e0 * l0 + e1 * l1);
    const s16x8 a = __builtin_nontemporal_load(
        reinterpret_cast<const s16x8*>(Op + (size_t)r * 512 + c8));
    const s16x8 bq = __builtin_nontemporal_load(
        reinterpret_cast<const s16x8*>(Op + (size_t)16384 * 512 + (size_t)r * 512 + c8));
    float o[8];
    #pragma unroll
    for (int i = 0; i < 8; i++)
        o[i] = (bf2f((unsigned short)a[i]) * e0 + bf2f((unsigned short)bq[i]) * e1) * invL;
    f32x4* dst = reinterpret_cast<f32x4*>(out + (size_t)r * 512 + c8);
    __builtin_nontemporal_store((f32x4){o[0], o[1], o[2], o[3]}, dst);
    __builtin_nontemporal_store((f32x4){o[4], o[5], o[6], o[7]}, dst + 1);
}

// ---------------- launch ----------------

extern "C" void kernel_launch(void* const* d_in, const int* in_sizes, int n_in,
                              void* d_out, int out_size, void* d_ws, size_t ws_size,
                              hipStream_t stream) {
    const float* x     = (const float*)d_in[0];
    const float* adj   = (const float*)d_in[1];
    const float* Wq    = (const float*)d_in[2];
    const float* bq    = (const float*)d_in[3];
    const float* Wk    = (const float*)d_in[4];
    const float* bk    = (const float*)d_in[5];
    const float* Wv    = (const float*)d_in[6];
    const float* bv    = (const float*)d_in[7];
    const float* scale = (const float*)d_in[8];
    const float* width = (const float*)d_in[9];

    char* ws = (char*)d_ws;
    unsigned short* xb = (unsigned short*)(ws);
    unsigned short* WT = (unsigned short*)(ws + 16777216);
    unsigned short* Qb = (unsigned short*)(ws + 18350080);
    unsigned short* Kb = (unsigned short*)(ws + 35127296);
    unsigned short* VT = (unsigned short*)(ws + 51904512);
    unsigned short* Op = (unsigned short*)(ws + 68681728);
    float*          Mp = (float*)(ws + 102236160);
    float*          Lp = (float*)(ws + 102367232);
    float* out = (float*)d_out;

    hipLaunchKernelGGL(convert_x_kernel, dim3(8192), dim3(256), 0, stream, x, xb, 8388608 / 4);
    hipLaunchKernelGGL(transpose_w_kernel, dim3(3072), dim3(256), 0, stream, Wq, Wk, Wv, WT);
    hipLaunchKernelGGL(proj_gemm_kernel, dim3(128, 4, 3), dim3(256), 0, stream,
                       xb, WT, bq, bk, bv, Qb, Kb, VT);
    hipLaunchKernelGGL(attn_kernel, dim3(512), dim3(512), 0, stream,
                       Qb, Kb, VT, adj, scale, width, Op, Mp, Lp);
    hipLaunchKernelGGL(combine_kernel, dim3(4096), dim3(256), 0, stream, Op, Mp, Lp, out);
}

// Round 13
// 286.586 us; speedup vs baseline: 1.6544x; 1.6544x over previous
//
#include <hip/hip_runtime.h>
#include <hip/hip_bf16.h>
#include <cstdint>

typedef __attribute__((ext_vector_type(4))) float f32x4;
typedef __attribute__((ext_vector_type(8))) short s16x8;

#define LOG2E 1.44269504088896340736f

#define WAITV0 asm volatile("s_waitcnt vmcnt(0)" ::: "memory")
#define WAITV2 asm volatile("s_waitcnt vmcnt(2)" ::: "memory")
#define WAITV18 asm volatile("s_waitcnt vmcnt(18)" ::: "memory")
#define WAITLG asm volatile("s_waitcnt lgkmcnt(0)" ::: "memory")
#define COMPILER_FENCE asm volatile("" ::: "memory")

__device__ __forceinline__ unsigned short f2bf(float f) {
    unsigned int u = __builtin_bit_cast(unsigned int, f);
    u += 0x7FFFu + ((u >> 16) & 1u);
    return (unsigned short)(u >> 16);
}
__device__ __forceinline__ float bf2f(unsigned short u) {
    return __builtin_bit_cast(float, (unsigned int)u << 16);
}
__device__ __forceinline__ void gload_lds16(const void* g, void* l) {
    __builtin_amdgcn_global_load_lds(
        (const __attribute__((address_space(1))) unsigned int*)g,
        (__attribute__((address_space(3))) unsigned int*)l, 16, 0, 0);
}
__device__ __forceinline__ int m3(int v) {   // v in [0, 11]
    if (v >= 9) v -= 9;
    if (v >= 6) v -= 6;
    if (v >= 3) v -= 3;
    return v;
}

// ---------------- prep kernels (ROUND-5 VERSIONS — proven 4.88e-4) ----------------

__global__ void convert_x_kernel(const float* __restrict__ x,
                                 unsigned short* __restrict__ xb, int n4) {
    int i = blockIdx.x * blockDim.x + threadIdx.x;
    if (i < n4) {
        const float4 v = reinterpret_cast<const float4*>(x)[i];
        ushort4 o;
        o.x = f2bf(v.x); o.y = f2bf(v.y); o.z = f2bf(v.z); o.w = f2bf(v.w);
        reinterpret_cast<ushort4*>(xb)[i] = o;
    }
}

// WT layout: [3][512 n][512 k], WT[m][n][k] = W_m[k][n]  (bf16)
__global__ void transpose_w_kernel(const float* __restrict__ Wq,
                                   const float* __restrict__ Wk,
                                   const float* __restrict__ Wv,
                                   unsigned short* __restrict__ WT) {
    int i = blockIdx.x * blockDim.x + threadIdx.x;
    int m = i >> 18;
    int r = i & 262143;
    int n = r & 511;
    int k = r >> 9;
    const float* W = (m == 0) ? Wq : (m == 1) ? Wk : Wv;
    WT[(m << 18) + n * 512 + k] = f2bf(W[k * 512 + n]);
}

// ---------------- projection GEMM (ROUND-5 VERSION — proven 4.88e-4) ----------------
__global__ __launch_bounds__(256, 2) void proj_gemm_kernel(
    const unsigned short* __restrict__ xb,
    const unsigned short* __restrict__ WT,
    const float* __restrict__ bq, const float* __restrict__ bk, const float* __restrict__ bv,
    unsigned short* __restrict__ Qb, unsigned short* __restrict__ Kb,
    unsigned short* __restrict__ VT)
{
    const int z = blockIdx.z;
    const unsigned short* Wt = WT + (z << 18);
    const float* bias = (z == 0) ? bq : (z == 1) ? bk : bv;

    const int gm = blockIdx.x * 128;
    const int gn = blockIdx.y * 128;
    const int wave = threadIdx.x >> 6, lane = threadIdx.x & 63;
    const int wr = wave >> 1, wc = wave & 1;
    const int lr = lane & 15, lg = lane >> 4;
    const int row0 = gm + wr * 64;
    const int col0 = gn + wc * 64;

    f32x4 acc[4][4];
    #pragma unroll
    for (int mi = 0; mi < 4; mi++)
        #pragma unroll
        for (int ni = 0; ni < 4; ni++)
            acc[mi][ni] = (f32x4){0.f, 0.f, 0.f, 0.f};

    for (int k0 = 0; k0 < 512; k0 += 32) {
        s16x8 a[4], b[4];
        #pragma unroll
        for (int mi = 0; mi < 4; mi++)
            a[mi] = *reinterpret_cast<const s16x8*>(xb + (size_t)(row0 + mi * 16 + lr) * 512 + k0 + lg * 8);
        #pragma unroll
        for (int ni = 0; ni < 4; ni++)
            b[ni] = *reinterpret_cast<const s16x8*>(Wt + (size_t)(col0 + ni * 16 + lr) * 512 + k0 + lg * 8);
        #pragma unroll
        for (int mi = 0; mi < 4; mi++)
            #pragma unroll
            for (int ni = 0; ni < 4; ni++)
                acc[mi][ni] = __builtin_amdgcn_mfma_f32_16x16x32_bf16(a[mi], b[ni], acc[mi][ni], 0, 0, 0);
    }

    #pragma unroll
    for (int ni = 0; ni < 4; ni++) {
        const int col = col0 + ni * 16 + lr;
        const float bs = bias[col];
        #pragma unroll
        for (int mi = 0; mi < 4; mi++) {
            const int rowb = row0 + mi * 16 + lg * 4;
            if (z == 2) {
                unsigned short h[4];
                #pragma unroll
                for (int j = 0; j < 4; j++) h[j] = f2bf(acc[mi][ni][j] + bs);
                const int bb = rowb >> 11;
                const int nn = rowb & 2047;
                ushort4 o; o.x = h[0]; o.y = h[1]; o.z = h[2]; o.w = h[3];
                *reinterpret_cast<ushort4*>(VT + (size_t)bb * (512 * 2048) + (size_t)col * 2048 + nn) = o;
            } else {
                unsigned short* dst = (z == 0) ? Qb : Kb;
                #pragma unroll
                for (int j = 0; j < 4; j++)
                    dst[(size_t)(rowb + j) * 512 + col] = f2bf(acc[mi][ni][j] + bs);
            }
        }
    }
}

// ---------------- fused masked attention: r11 structure, single-buffered pbuf/corr ----------------
// 512 blocks 1-D XCD-phased. 8 waves: 0-3 S, 4-7 O. LDS shrunk 68096 -> 58624 B
// so TWO blocks fit under a 128KB/CU allocation cap (the round-13 experiment).
// pbuf/corr single-buffer is epoch-safe: S writes at (t,7), O reads at (t+1,0),
// next S write at (t+1,7) — every conflicting pair is barrier-separated.
__global__ __launch_bounds__(512, 2) void attn_kernel(
    const unsigned short* __restrict__ Qb,
    const unsigned short* __restrict__ Kb,
    const unsigned short* __restrict__ VTb,
    const float* __restrict__ adj,
    const float* __restrict__ scale_p, const float* __restrict__ width_p,
    unsigned short* __restrict__ Op,
    float* __restrict__ Mp, float* __restrict__ Lp)
{
    const int bid = blockIdx.x;
    const int x8 = bid & 7, jj = bid >> 3;
    const int bk = x8 + 8 * (jj >> 5);
    const int qt = jj & 31;
    const int b    = bk >> 1;
    const int kvh  = bk & 1;
    const int wave = threadIdx.x >> 6;
    const int lane = threadIdx.x & 63;
    const int lr   = lane & 15;
    const int lg   = lane >> 4;

    // LDS carve: kring 3x8192 | vring 3x8192 | pbuf [4][16][72] | corr [64]  = 58624 B
    __shared__ __align__(16) char smem[58624];
    char* kring = smem;
    char* vring = smem + 24576;
    unsigned short (*pbuf)[16][72] = (unsigned short (*)[16][72])(smem + 49152);
    float* corrbuf = (float*)(smem + 58368);

    if (wave < 4) {
        // ================= S path: QK^T + mask + online softmax =================
        const int sw = wave;
        const int q0 = qt * 64 + sw * 16;
        const unsigned short* Qrow = Qb + ((size_t)b * 2048 + q0) * 512;
        const char* Kg = (const char*)Kb + ((size_t)b * 2048 + (size_t)kvh * 1024) * 1024;
        const float* adj_b = adj + (size_t)b * 2048 * 2048
                           + (size_t)(q0 + lg * 4) * 2048 + (size_t)kvh * 1024 + lr;
        const float scl = *scale_p;
        const float nw  = -LOG2E / (*width_p);
        const float cf  = 0.044194173824159216f * LOG2E;

        auto stage_k = [&](int slot, int c) {
            char* dstb = kring + slot * 8192;
            const int kvt = (c >> 3) * 64;
            const int dcb = (c & 7) * 128;
            #pragma unroll
            for (int i = 0; i < 2; i++) {
                const int sl  = sw * 2 + i;
                const int row = sl * 8 + (lane >> 3);
                const int colb = (lane & 7) * 16;
                gload_lds16(Kg + (size_t)(kvt + row) * 1024 + dcb + (colb ^ ((row & 7) << 4)),
                            dstb + sl * 1024);
            }
        };

        s16x8 qf[16];
        #pragma unroll
        for (int ks = 0; ks < 16; ks++)
            qf[ks] = __builtin_nontemporal_load(
                reinterpret_cast<const s16x8*>(Qrow + (size_t)lr * 512 + ks * 32 + lg * 8));

        f32x4 sacc[4];
        #pragma unroll
        for (int nt = 0; nt < 4; nt++) sacc[nt] = (f32x4){0.f, 0.f, 0.f, 0.f};
        float m_[4] = {-1e30f, -1e30f, -1e30f, -1e30f};
        float l_[4] = {0.f, 0.f, 0.f, 0.f};

        stage_k(0, 0);
        stage_k(1, 1);
        WAITV0;
        __builtin_amdgcn_s_barrier();

        int rcur = 0;   // (t*8) % 3
        for (int t = 0; t < 16; ++t) {
            const int kv0 = t * 64;
            float av[4][4];
            #pragma unroll
            for (int p = 0; p < 8; ++p) {
                const bool do_stage = (t < 15) || (p < 6);
                if (do_stage) stage_k(m3(rcur + p + 2), t * 8 + p + 2);

                if (p == 0) {
                    // adj for THIS tile: issue after stage (fence pins order),
                    // drained by p2's vmcnt(2) -> ~2.5 phases of latency cover.
                    COMPILER_FENCE;
                    #pragma unroll
                    for (int nt = 0; nt < 4; nt++)
                        #pragma unroll
                        for (int j = 0; j < 4; j++)
                            av[nt][j] = __builtin_nontemporal_load(
                                &adj_b[(size_t)j * 2048 + kv0 + nt * 16]);
                    COMPILER_FENCE;
                }

                const char* kb_ = kring + m3(rcur + p) * 8192;
                __builtin_amdgcn_s_setprio(1);
                #pragma unroll
                for (int ks = 0; ks < 2; ks++) {
                    const s16x8 a = qf[p * 2 + ks];
                    #pragma unroll
                    for (int nt = 0; nt < 4; nt++) {
                        const int row = nt * 16 + lr;
                        const int cbyte = ks * 64 + lg * 16;
                        const s16x8 kf = *reinterpret_cast<const s16x8*>(
                            kb_ + row * 128 + (cbyte ^ ((row & 7) << 4)));
                        sacc[nt] = __builtin_amdgcn_mfma_f32_16x16x32_bf16(a, kf, sacc[nt], 0, 0, 0);
                    }
                }
                __builtin_amdgcn_s_setprio(0);

                if (p == 7) {
                    // mask + online softmax; hand off P and corr via LDS (single buffer)
                    #pragma unroll
                    for (int nt = 0; nt < 4; nt++)
                        #pragma unroll
                        for (int j = 0; j < 4; j++) {
                            const float d = av[nt][j] - scl;
                            sacc[nt][j] = sacc[nt][j] * cf * exp2f(d * d * nw);
                        }
                    float corr[4];
                    #pragma unroll
                    for (int j = 0; j < 4; j++) {
                        float v = fmaxf(fmaxf(sacc[0][j], sacc[1][j]), fmaxf(sacc[2][j], sacc[3][j]));
                        #pragma unroll
                        for (int sh = 1; sh < 16; sh <<= 1) v = fmaxf(v, __shfl_xor(v, sh, 64));
                        const float mn = fmaxf(m_[j], v);
                        corr[j] = exp2f(m_[j] - mn);
                        m_[j] = mn;
                    }
                    #pragma unroll
                    for (int j = 0; j < 4; j++) {
                        float rs = 0.f;
                        #pragma unroll
                        for (int nt = 0; nt < 4; nt++) {
                            const float pv = exp2f(sacc[nt][j] - m_[j]);
                            pbuf[sw][lg * 4 + j][nt * 16 + lr] = f2bf(pv);
                            rs += pv;
                        }
                        #pragma unroll
                        for (int sh = 1; sh < 16; sh <<= 1) rs += __shfl_xor(rs, sh, 64);
                        l_[j] = l_[j] * corr[j] + rs;
                    }
                    if (lr == 0) {
                        #pragma unroll
                        for (int j = 0; j < 4; j++)
                            corrbuf[sw * 16 + lg * 4 + j] = corr[j];
                    }
                    #pragma unroll
                    for (int nt = 0; nt < 4; nt++) sacc[nt] = (f32x4){0.f, 0.f, 0.f, 0.f};
                    WAITLG;   // drain pbuf/corr ds_writes before barrier
                }
                // Derived waits (FIFO vmcnt; adj 16 in flight p0..p2):
                //  end p0/p1: vmcnt(18); end p2+: vmcnt(2); tail: vmcnt(0)
                if (p == 0 || p == 1) { WAITV18; }
                else if (do_stage)    { WAITV2; }
                else                  { WAITV0; }
                __builtin_amdgcn_s_barrier();
            }
            rcur += 2; if (rcur >= 3) rcur -= 3;
        }
        // trailing step t=16: barrier-match while O-waves finish PV(15)
        #pragma unroll
        for (int p = 0; p < 8; ++p) {
            WAITV0;
            __builtin_amdgcn_s_barrier();
        }
        const size_t prow0 = (size_t)kvh * 16384 + (size_t)b * 2048 + q0;
        if (lr == 0) {
            #pragma unroll
            for (int j = 0; j < 4; j++) {
                Mp[prow0 + lg * 4 + j] = m_[j];
                Lp[prow0 + lg * 4 + j] = l_[j];
            }
        }
    } else {
        // ================= O path: PV accumulate =================
        const int ow = wave - 4;
        const int q0 = qt * 64 + ow * 16;
        const char* Vg = (const char*)VTb + ((size_t)b * 512 * 2048 + (size_t)kvh * 1024) * 2;

        auto stage_v = [&](int slot, int c) {
            char* dstb = vring + slot * 8192;
            const int kvt = (c >> 3) * 64;
            const int dr0 = (c & 7) * 64;
            #pragma unroll
            for (int i = 0; i < 2; i++) {
                const int sl  = ow * 2 + i;
                const int row = sl * 8 + (lane >> 3);
                const int colb = (lane & 7) * 16;
                gload_lds16(Vg + (size_t)(dr0 + row) * 4096 + (size_t)kvt * 2 + (colb ^ ((row & 7) << 4)),
                            dstb + sl * 1024);
            }
        };

        f32x4 oacc[32];
        #pragma unroll
        for (int i = 0; i < 32; i++) oacc[i] = (f32x4){0.f, 0.f, 0.f, 0.f};
        s16x8 pa0{}, pa1{};

        __builtin_amdgcn_s_barrier();   // match S prologue

        // t = 0: no PV yet; start V stream at p=6,7 (chunks 0,1)
        #pragma unroll
        for (int p = 0; p < 8; ++p) {
            if (p == 6) stage_v(0, 0);
            if (p == 7) stage_v(1, 1);
            WAITV2;
            __builtin_amdgcn_s_barrier();
        }

        int rcur = 2;   // (t*8)%3 for t=1
        for (int t = 1; t < 17; ++t) {
            #pragma unroll
            for (int p = 0; p < 8; ++p) {
                const bool do_stage = (t < 16) || (p < 6);
                if (do_stage) stage_v(m3(rcur + p), t * 8 + p - 6);

                if (p == 0) {
                    const float* cl = corrbuf + ow * 16;
                    float c_[4];
                    #pragma unroll
                    for (int j = 0; j < 4; j++) c_[j] = cl[lg * 4 + j];
                    const unsigned short* pb = &pbuf[ow][0][0];
                    pa0 = *reinterpret_cast<const s16x8*>(pb + lr * 72 + lg * 8);
                    pa1 = *reinterpret_cast<const s16x8*>(pb + lr * 72 + 32 + lg * 8);
                    const bool need = __any(c_[0] < 1.f || c_[1] < 1.f || c_[2] < 1.f || c_[3] < 1.f);
                    if (need) {
                        #pragma unroll
                        for (int f = 0; f < 32; f++)
                            #pragma unroll
                            for (int j = 0; j < 4; j++) oacc[f][j] *= c_[j];
                    }
                }

                const char* vb_ = vring + m3(rcur + p + 1) * 8192;
                __builtin_amdgcn_s_setprio(1);
                #pragma unroll
                for (int ks2 = 0; ks2 < 2; ks2++) {
                    const s16x8 pa = (ks2 == 0) ? pa0 : pa1;
                    #pragma unroll
                    for (int df2 = 0; df2 < 4; df2++) {
                        const int row = df2 * 16 + lr;
                        const int cbyte = ks2 * 64 + lg * 16;
                        const s16x8 vf = *reinterpret_cast<const s16x8*>(
                            vb_ + row * 128 + (cbyte ^ ((row & 7) << 4)));
                        oacc[p * 4 + df2] = __builtin_amdgcn_mfma_f32_16x16x32_bf16(pa, vf, oacc[p * 4 + df2], 0, 0, 0);
                    }
                }
                __builtin_amdgcn_s_setprio(0);

                if (do_stage) { WAITV2; } else { WAITV0; }
                __builtin_amdgcn_s_barrier();
            }
            rcur += 2; if (rcur >= 3) rcur -= 3;
        }

        // ---- epilogue: LDS-transpose -> full-line nontemporal Op stores ----
        unsigned short* lds_t = (unsigned short*)smem + (size_t)ow * 4224;  // 16 x 264
        const size_t prow0 = (size_t)kvh * 16384 + (size_t)b * 2048 + q0;
        #pragma unroll
        for (int h = 0; h < 2; ++h) {
            #pragma unroll
            for (int dd = 0; dd < 16; ++dd) {
                const int df = h * 16 + dd;
                #pragma unroll
                for (int j = 0; j < 4; ++j)
                    lds_t[(lg * 4 + j) * 264 + dd * 16 + lr] = f2bf(oacc[df][j]);
            }
            #pragma unroll
            for (int g2 = 0; g2 < 2; ++g2) {
                const int r16  = g2 * 8 + (lane >> 3);
                const int colu = (lane & 7) * 8;
                unsigned short* oprow = Op + (prow0 + r16) * 512 + h * 256;
                #pragma unroll
                for (int k = 0; k < 4; ++k) {
                    const s16x8 v = *reinterpret_cast<const s16x8*>(&lds_t[r16 * 264 + colu + k * 64]);
                    __builtin_nontemporal_store(v, reinterpret_cast<s16x8*>(oprow + colu + k * 64));
                }
            }
        }
    }
}

// ---------------- combine ----------------
__global__ void combine_kernel(const unsigned short* __restrict__ Op,
                               const float* __restrict__ Mp, const float* __restrict__ Lp,
                               float* __restrict__ out) {
    const int idx = blockIdx.x * 256 + threadIdx.x;
    const int r   = idx >> 6;
    const int c8  = (idx & 63) * 8;
    const float m0 = Mp[r], m1 = Mp[16384 + r];
    const float l0 = Lp[r], l1 = Lp[16384 + r];
    const float M  = fmaxf(m0, m1);
    const float e0 = exp2f(m0 - M), e1 = exp2f(m1 - M);
    const float invL = 1.f / (e0 * l0 + e1 * l1);
    const s16x8 a = __builtin_nontemporal_load(
        reinterpret_cast<const s16x8*>(Op + (size_t)r * 512 + c8));
    const s16x8 bq = __builtin_nontemporal_load(
        reinterpret_cast<const s16x8*>(Op + (size_t)16384 * 512 + (size_t)r * 512 + c8));
    float o[8];
    #pragma unroll
    for (int i = 0; i < 8; i++)
        o[i] = (bf2f((unsigned short)a[i]) * e0 + bf2f((unsigned short)bq[i]) * e1) * invL;
    f32x4* dst = reinterpret_cast<f32x4*>(out + (size_t)r * 512 + c8);
    __builtin_nontemporal_store((f32x4){o[0], o[1], o[2], o[3]}, dst);
    __builtin_nontemporal_store((f32x4){o[4], o[5], o[6], o[7]}, dst + 1);
}

// ---------------- launch ----------------

extern "C" void kernel_launch(void* const* d_in, const int* in_sizes, int n_in,
                              void* d_out, int out_size, void* d_ws, size_t ws_size,
                              hipStream_t stream) {
    const float* x     = (const float*)d_in[0];
    const float* adj   = (const float*)d_in[1];
    const float* Wq    = (const float*)d_in[2];
    const float* bq    = (const float*)d_in[3];
    const float* Wk    = (const float*)d_in[4];
    const float* bk    = (const float*)d_in[5];
    const float* Wv    = (const float*)d_in[6];
    const float* bv    = (const float*)d_in[7];
    const float* scale = (const float*)d_in[8];
    const float* width = (const float*)d_in[9];

    char* ws = (char*)d_ws;
    unsigned short* xb = (unsigned short*)(ws);
    unsigned short* WT = (unsigned short*)(ws + 16777216);
    unsigned short* Qb = (unsigned short*)(ws + 18350080);
    unsigned short* Kb = (unsigned short*)(ws + 35127296);
    unsigned short* VT = (unsigned short*)(ws + 51904512);
    unsigned short* Op = (unsigned short*)(ws + 68681728);
    float*          Mp = (float*)(ws + 102236160);
    float*          Lp = (float*)(ws + 102367232);
    float* out = (float*)d_out;

    hipLaunchKernelGGL(convert_x_kernel, dim3(8192), dim3(256), 0, stream, x, xb, 8388608 / 4);
    hipLaunchKernelGGL(transpose_w_kernel, dim3(3072), dim3(256), 0, stream, Wq, Wk, Wv, WT);
    hipLaunchKernelGGL(proj_gemm_kernel, dim3(128, 4, 3), dim3(256), 0, stream,
                       xb, WT, bq, bk, bv, Qb, Kb, VT);
    hipLaunchKernelGGL(attn_kernel, dim3(512), dim3(512), 0, stream,
                       Qb, Kb, VT, adj, scale, width, Op, Mp, Lp);
    hipLaunchKernelGGL(combine_kernel, dim3(4096), dim3(256), 0, stream, Op, Mp, Lp, out);
}

// Round 14
// 282.180 us; speedup vs baseline: 1.6803x; 1.0156x over previous
//
#include <hip/hip_runtime.h>
#include <hip/hip_bf16.h>
#include <cstdint>

typedef __attribute__((ext_vector_type(4))) float f32x4;
typedef __attribute__((ext_vector_type(8))) short s16x8;

#define LOG2E 1.44269504088896340736f

#define WAITV0 asm volatile("s_waitcnt vmcnt(0)" ::: "memory")
#define WAITV4 asm volatile("s_waitcnt vmcnt(4)" ::: "memory")
#define WAITV20 asm volatile("s_waitcnt vmcnt(20)" ::: "memory")
#define WAITLG asm volatile("s_waitcnt lgkmcnt(0)" ::: "memory")
#define COMPILER_FENCE asm volatile("" ::: "memory")

__device__ __forceinline__ unsigned short f2bf(float f) {
    unsigned int u = __builtin_bit_cast(unsigned int, f);
    u += 0x7FFFu + ((u >> 16) & 1u);
    return (unsigned short)(u >> 16);
}
__device__ __forceinline__ float bf2f(unsigned short u) {
    return __builtin_bit_cast(float, (unsigned int)u << 16);
}
__device__ __forceinline__ void gload_lds16(const void* g, void* l) {
    __builtin_amdgcn_global_load_lds(
        (const __attribute__((address_space(1))) unsigned int*)g,
        (__attribute__((address_space(3))) unsigned int*)l, 16, 0, 0);
}

// ---------------- prep kernels (ROUND-5 VERSIONS — proven 4.88e-4) ----------------

__global__ void convert_x_kernel(const float* __restrict__ x,
                                 unsigned short* __restrict__ xb, int n4) {
    int i = blockIdx.x * blockDim.x + threadIdx.x;
    if (i < n4) {
        const float4 v = reinterpret_cast<const float4*>(x)[i];
        ushort4 o;
        o.x = f2bf(v.x); o.y = f2bf(v.y); o.z = f2bf(v.z); o.w = f2bf(v.w);
        reinterpret_cast<ushort4*>(xb)[i] = o;
    }
}

// WT layout: [3][512 n][512 k], WT[m][n][k] = W_m[k][n]  (bf16)
__global__ void transpose_w_kernel(const float* __restrict__ Wq,
                                   const float* __restrict__ Wk,
                                   const float* __restrict__ Wv,
                                   unsigned short* __restrict__ WT) {
    int i = blockIdx.x * blockDim.x + threadIdx.x;
    int m = i >> 18;
    int r = i & 262143;
    int n = r & 511;
    int k = r >> 9;
    const float* W = (m == 0) ? Wq : (m == 1) ? Wk : Wv;
    WT[(m << 18) + n * 512 + k] = f2bf(W[k * 512 + n]);
}

// ---------------- projection GEMM (ROUND-5 VERSION — proven 4.88e-4) ----------------
__global__ __launch_bounds__(256, 2) void proj_gemm_kernel(
    const unsigned short* __restrict__ xb,
    const unsigned short* __restrict__ WT,
    const float* __restrict__ bq, const float* __restrict__ bk, const float* __restrict__ bv,
    unsigned short* __restrict__ Qb, unsigned short* __restrict__ Kb,
    unsigned short* __restrict__ VT)
{
    const int z = blockIdx.z;
    const unsigned short* Wt = WT + (z << 18);
    const float* bias = (z == 0) ? bq : (z == 1) ? bk : bv;

    const int gm = blockIdx.x * 128;
    const int gn = blockIdx.y * 128;
    const int wave = threadIdx.x >> 6, lane = threadIdx.x & 63;
    const int wr = wave >> 1, wc = wave & 1;
    const int lr = lane & 15, lg = lane >> 4;
    const int row0 = gm + wr * 64;
    const int col0 = gn + wc * 64;

    f32x4 acc[4][4];
    #pragma unroll
    for (int mi = 0; mi < 4; mi++)
        #pragma unroll
        for (int ni = 0; ni < 4; ni++)
            acc[mi][ni] = (f32x4){0.f, 0.f, 0.f, 0.f};

    for (int k0 = 0; k0 < 512; k0 += 32) {
        s16x8 a[4], b[4];
        #pragma unroll
        for (int mi = 0; mi < 4; mi++)
            a[mi] = *reinterpret_cast<const s16x8*>(xb + (size_t)(row0 + mi * 16 + lr) * 512 + k0 + lg * 8);
        #pragma unroll
        for (int ni = 0; ni < 4; ni++)
            b[ni] = *reinterpret_cast<const s16x8*>(Wt + (size_t)(col0 + ni * 16 + lr) * 512 + k0 + lg * 8);
        #pragma unroll
        for (int mi = 0; mi < 4; mi++)
            #pragma unroll
            for (int ni = 0; ni < 4; ni++)
                acc[mi][ni] = __builtin_amdgcn_mfma_f32_16x16x32_bf16(a[mi], b[ni], acc[mi][ni], 0, 0, 0);
    }

    #pragma unroll
    for (int ni = 0; ni < 4; ni++) {
        const int col = col0 + ni * 16 + lr;
        const float bs = bias[col];
        #pragma unroll
        for (int mi = 0; mi < 4; mi++) {
            const int rowb = row0 + mi * 16 + lg * 4;
            if (z == 2) {
                unsigned short h[4];
                #pragma unroll
                for (int j = 0; j < 4; j++) h[j] = f2bf(acc[mi][ni][j] + bs);
                const int bb = rowb >> 11;
                const int nn = rowb & 2047;
                ushort4 o; o.x = h[0]; o.y = h[1]; o.z = h[2]; o.w = h[3];
                *reinterpret_cast<ushort4*>(VT + (size_t)bb * (512 * 2048) + (size_t)col * 2048 + nn) = o;
            } else {
                unsigned short* dst = (z == 0) ? Qb : Kb;
                #pragma unroll
                for (int j = 0; j < 4; j++)
                    dst[(size_t)(rowb + j) * 512 + col] = f2bf(acc[mi][ni][j] + bs);
            }
        }
    }
}

// ---------------- fused masked attention: wave-specialized, 128-d phases ----------------
// 512 blocks 1-D XCD-phased. 8 waves: 0-3 S, 4-7 O.
// K/V chunks = 128 d (16KB), ring-3 each, 4 phases/tile: barriers 137 -> 69.
// Waits (FIFO vmcnt): S p0/p1=20 (4-deep stage + 16 adj), p2/p3=4; O=4; tails=0.
// pbuf/corr single-buffered (epoch-safe per r13).
__global__ __launch_bounds__(512, 2) void attn_kernel(
    const unsigned short* __restrict__ Qb,
    const unsigned short* __restrict__ Kb,
    const unsigned short* __restrict__ VTb,
    const float* __restrict__ adj,
    const float* __restrict__ scale_p, const float* __restrict__ width_p,
    unsigned short* __restrict__ Op,
    float* __restrict__ Mp, float* __restrict__ Lp)
{
    const int bid = blockIdx.x;
    const int x8 = bid & 7, jj = bid >> 3;
    const int bk = x8 + 8 * (jj >> 5);
    const int qt = jj & 31;
    const int b    = bk >> 1;
    const int kvh  = bk & 1;
    const int wave = threadIdx.x >> 6;
    const int lane = threadIdx.x & 63;
    const int lr   = lane & 15;
    const int lg   = lane >> 4;

    // LDS carve: kring 3x16384 | vring 3x16384 | pbuf [4][16][72] | corr [64] = 107776 B
    __shared__ __align__(16) char smem[107776];
    char* kring = smem;
    char* vring = smem + 49152;
    unsigned short (*pbuf)[16][72] = (unsigned short (*)[16][72])(smem + 98304);
    float* corrbuf = (float*)(smem + 107520);

    if (wave < 4) {
        // ================= S path: QK^T + mask + online softmax =================
        const int sw = wave;
        const int q0 = qt * 64 + sw * 16;
        const unsigned short* Qrow = Qb + ((size_t)b * 2048 + q0) * 512;
        const char* Kg = (const char*)Kb + ((size_t)b * 2048 + (size_t)kvh * 1024) * 1024;
        const float* adj_b = adj + (size_t)b * 2048 * 2048
                           + (size_t)(q0 + lg * 4) * 2048 + (size_t)kvh * 1024 + lr;
        const float scl = *scale_p;
        const float nw  = -LOG2E / (*width_p);
        const float cf  = 0.044194173824159216f * LOG2E;

        // K chunk c (tile c>>2, d-block c&3): [64 kv][256 B], source pre-swizzled.
        auto stage_k = [&](int slot, int c) {
            char* dstb = kring + slot * 16384;
            const int kvt = (c >> 2) * 64;
            const int dcb = (c & 3) * 256;
            #pragma unroll
            for (int i = 0; i < 4; i++) {
                const int sl  = sw * 4 + i;              // 0..15
                const int row = sl * 4 + (lane >> 4);    // 0..63
                const int colb = (lane & 15) * 16;       // 0..240
                gload_lds16(Kg + (size_t)(kvt + row) * 1024 + dcb + (colb ^ ((row & 7) << 4)),
                            dstb + sl * 1024);
            }
        };

        s16x8 qf[16];
        #pragma unroll
        for (int ks = 0; ks < 16; ks++)
            qf[ks] = __builtin_nontemporal_load(
                reinterpret_cast<const s16x8*>(Qrow + (size_t)lr * 512 + ks * 32 + lg * 8));

        f32x4 sacc[4];
        #pragma unroll
        for (int nt = 0; nt < 4; nt++) sacc[nt] = (f32x4){0.f, 0.f, 0.f, 0.f};
        float m_[4] = {-1e30f, -1e30f, -1e30f, -1e30f};
        float l_[4] = {0.f, 0.f, 0.f, 0.f};

        stage_k(0, 0);
        stage_k(1, 1);
        WAITV0;
        __builtin_amdgcn_s_barrier();

        int cs = 0, ss = 2;   // compute slot for chunk g, stage slot for chunk g+2
        for (int t = 0; t < 16; ++t) {
            const int kv0 = t * 64;
            float av[4][4];
            #pragma unroll
            for (int p = 0; p < 4; ++p) {
                const int c_s = t * 4 + p + 2;
                const bool do_stage = (c_s <= 63);
                if (do_stage) stage_k(ss, c_s);

                if (p == 0) {
                    // adj for THIS tile (used at p3): issue after stage, fences pin order
                    COMPILER_FENCE;
                    #pragma unroll
                    for (int nt = 0; nt < 4; nt++)
                        #pragma unroll
                        for (int j = 0; j < 4; j++)
                            av[nt][j] = __builtin_nontemporal_load(
                                &adj_b[(size_t)j * 2048 + kv0 + nt * 16]);
                    COMPILER_FENCE;
                }

                const char* kb_ = kring + cs * 16384;
                __builtin_amdgcn_s_setprio(1);
                #pragma unroll
                for (int ks = 0; ks < 4; ks++) {
                    const s16x8 a = qf[p * 4 + ks];
                    #pragma unroll
                    for (int nt = 0; nt < 4; nt++) {
                        const int row = nt * 16 + lr;
                        const int cbyte = ks * 64 + lg * 16;
                        const s16x8 kf = *reinterpret_cast<const s16x8*>(
                            kb_ + row * 256 + (cbyte ^ ((row & 7) << 4)));
                        sacc[nt] = __builtin_amdgcn_mfma_f32_16x16x32_bf16(a, kf, sacc[nt], 0, 0, 0);
                    }
                }
                __builtin_amdgcn_s_setprio(0);

                if (p == 3) {
                    // mask + online softmax; hand off P and corr via LDS (single buffer)
                    #pragma unroll
                    for (int nt = 0; nt < 4; nt++)
                        #pragma unroll
                        for (int j = 0; j < 4; j++) {
                            const float d = av[nt][j] - scl;
                            sacc[nt][j] = sacc[nt][j] * cf * exp2f(d * d * nw);
                        }
                    float corr[4];
                    #pragma unroll
                    for (int j = 0; j < 4; j++) {
                        float v = fmaxf(fmaxf(sacc[0][j], sacc[1][j]), fmaxf(sacc[2][j], sacc[3][j]));
                        #pragma unroll
                        for (int sh = 1; sh < 16; sh <<= 1) v = fmaxf(v, __shfl_xor(v, sh, 64));
                        const float mn = fmaxf(m_[j], v);
                        corr[j] = exp2f(m_[j] - mn);
                        m_[j] = mn;
                    }
                    #pragma unroll
                    for (int j = 0; j < 4; j++) {
                        float rs = 0.f;
                        #pragma unroll
                        for (int nt = 0; nt < 4; nt++) {
                            const float pv = exp2f(sacc[nt][j] - m_[j]);
                            pbuf[sw][lg * 4 + j][nt * 16 + lr] = f2bf(pv);
                            rs += pv;
                        }
                        #pragma unroll
                        for (int sh = 1; sh < 16; sh <<= 1) rs += __shfl_xor(rs, sh, 64);
                        l_[j] = l_[j] * corr[j] + rs;
                    }
                    if (lr == 0) {
                        #pragma unroll
                        for (int j = 0; j < 4; j++)
                            corrbuf[sw * 16 + lg * 4 + j] = corr[j];
                    }
                    #pragma unroll
                    for (int nt = 0; nt < 4; nt++) sacc[nt] = (f32x4){0.f, 0.f, 0.f, 0.f};
                    WAITLG;   // drain pbuf/corr ds_writes before barrier
                }
                // Derived waits (FIFO): p0/p1 drain 2-phases-ago stage -> vmcnt(20)
                // (leaves own 4 + adj 16); p2/p3 -> vmcnt(4) (drains older stage + adj
                // before its p3 use); no-stage tail -> vmcnt(0).
                if (p <= 1)        { WAITV20; }
                else if (do_stage) { WAITV4; }
                else               { WAITV0; }
                __builtin_amdgcn_s_barrier();
                cs = (cs == 2) ? 0 : cs + 1;
                ss = (ss == 2) ? 0 : ss + 1;
            }
        }
        // trailing idle tile (4 barriers): O-waves finish PV(15)
        #pragma unroll
        for (int p = 0; p < 4; ++p) {
            WAITV0;
            __builtin_amdgcn_s_barrier();
        }
        const size_t prow0 = (size_t)kvh * 16384 + (size_t)b * 2048 + q0;
        if (lr == 0) {
            #pragma unroll
            for (int j = 0; j < 4; j++) {
                Mp[prow0 + lg * 4 + j] = m_[j];
                Lp[prow0 + lg * 4 + j] = l_[j];
            }
        }
    } else {
        // ================= O path: PV accumulate (one tile behind S) =================
        const int ow = wave - 4;
        const int q0 = qt * 64 + ow * 16;
        const char* Vg = (const char*)VTb + ((size_t)b * 512 * 2048 + (size_t)kvh * 1024) * 2;

        // V chunk c (tile c>>2, d-block c&3): [128 d][128 B], source pre-swizzled.
        auto stage_v = [&](int slot, int c) {
            char* dstb = vring + slot * 16384;
            const int kvt = (c >> 2) * 64;
            const int dr0 = (c & 3) * 128;
            #pragma unroll
            for (int i = 0; i < 4; i++) {
                const int sl  = ow * 4 + i;              // 0..15
                const int row = sl * 8 + (lane >> 3);    // 0..127
                const int colb = (lane & 7) * 16;        // 0..112
                gload_lds16(Vg + (size_t)(dr0 + row) * 4096 + (size_t)kvt * 2 + (colb ^ ((row & 7) << 4)),
                            dstb + sl * 1024);
            }
        };

        f32x4 oacc[32];
        #pragma unroll
        for (int i = 0; i < 32; i++) oacc[i] = (f32x4){0.f, 0.f, 0.f, 0.f};
        s16x8 pa0{}, pa1{};

        __builtin_amdgcn_s_barrier();   // match S prologue

        // idle tile t=0: start V stream (chunk0->slot0 at p2, chunk1->slot1 at p3)
        #pragma unroll
        for (int p = 0; p < 4; ++p) {
            if (p == 2) stage_v(0, 0);
            if (p == 3) stage_v(1, 1);
            if (p >= 2) { WAITV4; } else { WAITV0; }
            __builtin_amdgcn_s_barrier();
        }

        int cs = 0, ss = 2;   // compute chunk g-4 (slot), stage chunk g-2 (slot)
        for (int t = 1; t < 17; ++t) {
            #pragma unroll
            for (int p = 0; p < 4; ++p) {
                const int c_s = t * 4 + p - 2;
                const bool do_stage = (c_s <= 63);
                if (do_stage) stage_v(ss, c_s);

                if (p == 0) {
                    const float* cl = corrbuf + ow * 16;
                    float c_[4];
                    #pragma unroll
                    for (int j = 0; j < 4; j++) c_[j] = cl[lg * 4 + j];
                    const unsigned short* pb = &pbuf[ow][0][0];
                    pa0 = *reinterpret_cast<const s16x8*>(pb + lr * 72 + lg * 8);
                    pa1 = *reinterpret_cast<const s16x8*>(pb + lr * 72 + 32 + lg * 8);
                    const bool need = __any(c_[0] < 1.f || c_[1] < 1.f || c_[2] < 1.f || c_[3] < 1.f);
                    if (need) {
                        #pragma unroll
                        for (int f = 0; f < 32; f++)
                            #pragma unroll
                            for (int j = 0; j < 4; j++) oacc[f][j] *= c_[j];
                    }
                }

                const char* vb_ = vring + cs * 16384;
                __builtin_amdgcn_s_setprio(1);
                #pragma unroll
                for (int ks2 = 0; ks2 < 2; ks2++) {
                    const s16x8 pa = (ks2 == 0) ? pa0 : pa1;
                    #pragma unroll
                    for (int df2 = 0; df2 < 8; df2++) {
                        const int row = df2 * 16 + lr;   // 0..127 within chunk
                        const int cbyte = ks2 * 64 + lg * 16;
                        const s16x8 vf = *reinterpret_cast<const s16x8*>(
                            vb_ + row * 128 + (cbyte ^ ((row & 7) << 4)));
                        oacc[p * 8 + df2] = __builtin_amdgcn_mfma_f32_16x16x32_bf16(pa, vf, oacc[p * 8 + df2], 0, 0, 0);
                    }
                }
                __builtin_amdgcn_s_setprio(0);

                if (do_stage) { WAITV4; } else { WAITV0; }
                __builtin_amdgcn_s_barrier();
                cs = (cs == 2) ? 0 : cs + 1;
                ss = (ss == 2) ? 0 : ss + 1;
            }
        }

        // ---- epilogue: LDS-transpose -> full-line nontemporal Op stores ----
        unsigned short* lds_t = (unsigned short*)smem + (size_t)ow * 4224;  // 16 x 264
        const size_t prow0 = (size_t)kvh * 16384 + (size_t)b * 2048 + q0;
        #pragma unroll
        for (int h = 0; h < 2; ++h) {
            #pragma unroll
            for (int dd = 0; dd < 16; ++dd) {
                const int df = h * 16 + dd;
                #pragma unroll
                for (int j = 0; j < 4; ++j)
                    lds_t[(lg * 4 + j) * 264 + dd * 16 + lr] = f2bf(oacc[df][j]);
            }
            #pragma unroll
            for (int g2 = 0; g2 < 2; ++g2) {
                const int r16  = g2 * 8 + (lane >> 3);
                const int colu = (lane & 7) * 8;
                unsigned short* oprow = Op + (prow0 + r16) * 512 + h * 256;
                #pragma unroll
                for (int k = 0; k < 4; ++k) {
                    const s16x8 v = *reinterpret_cast<const s16x8*>(&lds_t[r16 * 264 + colu + k * 64]);
                    __builtin_nontemporal_store(v, reinterpret_cast<s16x8*>(oprow + colu + k * 64));
                }
            }
        }
    }
}

// ---------------- combine ----------------
__global__ void combine_kernel(const unsigned short* __restrict__ Op,
                               const float* __restrict__ Mp, const float* __restrict__ Lp,
                               float* __restrict__ out) {
    const int idx = blockIdx.x * 256 + threadIdx.x;
    const int r   = idx >> 6;
    const int c8  = (idx & 63) * 8;
    const float m0 = Mp[r], m1 = Mp[16384 + r];
    const float l0 = Lp[r], l1 = Lp[16384 + r];
    const float M  = fmaxf(m0, m1);
    const float e0 = exp2f(m0 - M), e1 = exp2f(m1 - M);
    const float invL = 1.f / (e0 * l0 + e1 * l1);
    const s16x8 a = __builtin_nontemporal_load(
        reinterpret_cast<const s16x8*>(Op + (size_t)r * 512 + c8));
    const s16x8 bq = __builtin_nontemporal_load(
        reinterpret_cast<const s16x8*>(Op + (size_t)16384 * 512 + (size_t)r * 512 + c8));
    float o[8];
    #pragma unroll
    for (int i = 0; i < 8; i++)
        o[i] = (bf2f((unsigned short)a[i]) * e0 + bf2f((unsigned short)bq[i]) * e1) * invL;
    f32x4* dst = reinterpret_cast<f32x4*>(out + (size_t)r * 512 + c8);
    __builtin_nontemporal_store((f32x4){o[0], o[1], o[2], o[3]}, dst);
    __builtin_nontemporal_store((f32x4){o[4], o[5], o[6], o[7]}, dst + 1);
}

// ---------------- launch ----------------

extern "C" void kernel_launch(void* const* d_in, const int* in_sizes, int n_in,
                              void* d_out, int out_size, void* d_ws, size_t ws_size,
                              hipStream_t stream) {
    const float* x     = (const float*)d_in[0];
    const float* adj   = (const float*)d_in[1];
    const float* Wq    = (const float*)d_in[2];
    const float* bq    = (const float*)d_in[3];
    const float* Wk    = (const float*)d_in[4];
    const float* bk    = (const float*)d_in[5];
    const float* Wv    = (const float*)d_in[6];
    const float* bv    = (const float*)d_in[7];
    const float* scale = (const float*)d_in[8];
    const float* width = (const float*)d_in[9];

    char* ws = (char*)d_ws;
    unsigned short* xb = (unsigned short*)(ws);
    unsigned short* WT = (unsigned short*)(ws + 16777216);
    unsigned short* Qb = (unsigned short*)(ws + 18350080);
    unsigned short* Kb = (unsigned short*)(ws + 35127296);
    unsigned short* VT = (unsigned short*)(ws + 51904512);
    unsigned short* Op = (unsigned short*)(ws + 68681728);
    float*          Mp = (float*)(ws + 102236160);
    float*          Lp = (float*)(ws + 102367232);
    float* out = (float*)d_out;

    hipLaunchKernelGGL(convert_x_kernel, dim3(8192), dim3(256), 0, stream, x, xb, 8388608 / 4);
    hipLaunchKernelGGL(transpose_w_kernel, dim3(3072), dim3(256), 0, stream, Wq, Wk, Wv, WT);
    hipLaunchKernelGGL(proj_gemm_kernel, dim3(128, 4, 3), dim3(256), 0, stream,
                       xb, WT, bq, bk, bv, Qb, Kb, VT);
    hipLaunchKernelGGL(attn_kernel, dim3(512), dim3(512), 0, stream,
                       Qb, Kb, VT, adj, scale, width, Op, Mp, Lp);
    hipLaunchKernelGGL(combine_kernel, dim3(4096), dim3(256), 0, stream, Op, Mp, Lp, out);
}